// Round 1
// baseline (12.501 us; speedup 1.0000x reference)
//
#include <hip/hip_runtime.h>

// QuanvolutionHybrid — closed-form quantum circuit + fused matvec + log_softmax.
//
// Math: the 4-qubit circuit per patch reduces to per-wire Z expectations
//   z0 = cos(p0 + q0), z1 = cos(p1)*cos(q1), z2 = cos(p2 + q2), z3 = cos(p3)*cos(q3)
// and, after the CNOT chain (pure basis permutation, final bits are XORs of
// initial independent bits), measured features
//   f0 = z1*z2*z3, f1 = z0*z1, f2 = z0*z1*z2, f3 = z0*z1*z2*z3.
// Then logits = features @ W^T + b, out = log_softmax(logits).

constexpr int NPIX = 784;   // 28*28
constexpr int NP   = 196;   // 14*14 patches
constexpr int NCLS = 10;

__global__ __launch_bounds__(256)
void quanv_fused(const float* __restrict__ x,     // [B,784]
                 const float* __restrict__ qp,    // [4]
                 const float* __restrict__ W,     // [10,784]
                 const float* __restrict__ bias,  // [10]
                 float* __restrict__ out)         // [B,10]
{
    const int b   = blockIdx.x;
    const int tid = threadIdx.x;

    // broadcast circuit params (tiny, L2-hit, uniform across lanes)
    const float t0 = qp[0];
    const float c1 = __cosf(qp[1]);
    const float t2 = qp[2];
    const float c3 = __cosf(qp[3]);

    float part[NCLS];
#pragma unroll
    for (int j = 0; j < NCLS; ++j) part[j] = 0.f;

    if (tid < NP) {
        const int pr = tid / 14;
        const int pc = tid - pr * 14;
        // pixels (x[r,c], x[r,c+1], x[r+1,c], x[r+1,c+1]) for r=2*pr, c=2*pc
        const float* xrow = x + b * NPIX + (2 * pr) * 28 + 2 * pc;
        const float2 top = *reinterpret_cast<const float2*>(xrow);       // p0,p1
        const float2 bot = *reinterpret_cast<const float2*>(xrow + 28);  // p2,p3

        const float z0 = __cosf(top.x + t0);
        const float z1 = __cosf(top.y) * c1;
        const float z2 = __cosf(bot.x + t2);
        const float z3 = __cosf(bot.y) * c3;

        const float f1 = z0 * z1;
        const float f2 = f1 * z2;
        const float f3 = f2 * z3;
        const float f0 = z1 * z2 * z3;

        // W[j][4*tid .. 4*tid+3] as float4; row stride 784 floats = 196 float4
        const float4* Wp = reinterpret_cast<const float4*>(W) + tid;
#pragma unroll
        for (int j = 0; j < NCLS; ++j) {
            const float4 w = Wp[j * (NPIX / 4)];
            part[j] = fmaf(f0, w.x, fmaf(f1, w.y, fmaf(f2, w.z, f3 * w.w)));
        }
    }

    // wave(64)-wide shuffle reduction of the 10 partials
#pragma unroll
    for (int off = 32; off > 0; off >>= 1) {
#pragma unroll
        for (int j = 0; j < NCLS; ++j)
            part[j] += __shfl_down(part[j], off, 64);
    }

    __shared__ float sred[4][NCLS];
    const int wave = tid >> 6;
    const int lane = tid & 63;
    if (lane == 0) {
#pragma unroll
        for (int j = 0; j < NCLS; ++j) sred[wave][j] = part[j];
    }
    __syncthreads();

    if (tid == 0) {
        float logit[NCLS];
        float m = -1e30f;
#pragma unroll
        for (int j = 0; j < NCLS; ++j) {
            logit[j] = sred[0][j] + sred[1][j] + sred[2][j] + sred[3][j] + bias[j];
            m = fmaxf(m, logit[j]);
        }
        float s = 0.f;
#pragma unroll
        for (int j = 0; j < NCLS; ++j) s += __expf(logit[j] - m);
        const float lse = m + __logf(s);
        float* o = out + b * NCLS;
#pragma unroll
        for (int j = 0; j < NCLS; ++j) o[j] = logit[j] - lse;
    }
}

extern "C" void kernel_launch(void* const* d_in, const int* in_sizes, int n_in,
                              void* d_out, int out_size, void* d_ws, size_t ws_size,
                              hipStream_t stream) {
    const float* x    = (const float*)d_in[0];
    const float* qp   = (const float*)d_in[1];
    const float* W    = (const float*)d_in[2];
    const float* bias = (const float*)d_in[3];
    float* out = (float*)d_out;

    const int B = in_sizes[0] / NPIX;  // 2048
    quanv_fused<<<B, 256, 0, stream>>>(x, qp, W, bias, out);
}

// Round 2
// 10.286 us; speedup vs baseline: 1.2154x; 1.2154x over previous
//
#include <hip/hip_runtime.h>

// QuanvolutionHybrid — closed-form quantum circuit + fused matvec + log_softmax.
//
// Math: the 4-qubit circuit per patch reduces to per-wire Z expectations
//   z0 = cos(p0 + q0), z1 = cos(p1)*cos(q1), z2 = cos(p2 + q2), z3 = cos(p3)*cos(q3)
// and, after the CNOT chain (pure basis permutation, final bits are XORs of
// initial independent bits), measured features
//   f0 = z1*z2*z3, f1 = z0*z1, f2 = z0*z1*z2, f3 = z0*z1*z2*z3.
// Then logits = features @ W^T + b, out = log_softmax(logits).
//
// R1 change: wave reduction via DPP VALU adds (row_shr:1/2/4/8 + row_bcast:15/31,
// the LLVM atomic-optimizer sequence) instead of 60 DS-pipe __shfl_down ops.

constexpr int NPIX = 784;   // 28*28
constexpr int NP   = 196;   // 14*14 patches
constexpr int NCLS = 10;

template <int Ctrl, int RowMask>
__device__ __forceinline__ float dpp_add(float x) {
    // x + dpp_shifted(x); invalid/masked source lanes contribute 0 (old = 0).
    int s = __builtin_amdgcn_update_dpp(0, __float_as_int(x), Ctrl, RowMask, 0xf, false);
    return x + __int_as_float(s);
}

__global__ __launch_bounds__(256)
void quanv_fused(const float* __restrict__ x,     // [B,784]
                 const float* __restrict__ qp,    // [4]
                 const float* __restrict__ W,     // [10,784]
                 const float* __restrict__ bias,  // [10]
                 float* __restrict__ out)         // [B,10]
{
    const int b   = blockIdx.x;
    const int tid = threadIdx.x;

    const float t0 = qp[0];
    const float c1 = __cosf(qp[1]);
    const float t2 = qp[2];
    const float c3 = __cosf(qp[3]);

    float part[NCLS];
#pragma unroll
    for (int j = 0; j < NCLS; ++j) part[j] = 0.f;

    if (tid < NP) {
        const int pr = tid / 14;
        const int pc = tid - pr * 14;
        const float* xrow = x + b * NPIX + (2 * pr) * 28 + 2 * pc;
        const float2 top = *reinterpret_cast<const float2*>(xrow);       // p0,p1
        const float2 bot = *reinterpret_cast<const float2*>(xrow + 28);  // p2,p3

        const float z0 = __cosf(top.x + t0);
        const float z1 = __cosf(top.y) * c1;
        const float z2 = __cosf(bot.x + t2);
        const float z3 = __cosf(bot.y) * c3;

        const float f1 = z0 * z1;
        const float f2 = f1 * z2;
        const float f3 = f2 * z3;
        const float f0 = z1 * z2 * z3;

        const float4* Wp = reinterpret_cast<const float4*>(W) + tid;
#pragma unroll
        for (int j = 0; j < NCLS; ++j) {
            const float4 w = Wp[j * (NPIX / 4)];
            part[j] = fmaf(f0, w.x, fmaf(f1, w.y, fmaf(f2, w.z, f3 * w.w)));
        }
    }

    // DPP wave(64) reduction: sum lands in lane 63 of each wave. Pure VALU.
#pragma unroll
    for (int j = 0; j < NCLS; ++j) {
        float v = part[j];
        v = dpp_add<0x111, 0xf>(v);  // row_shr:1
        v = dpp_add<0x112, 0xf>(v);  // row_shr:2
        v = dpp_add<0x114, 0xf>(v);  // row_shr:4
        v = dpp_add<0x118, 0xf>(v);  // row_shr:8
        v = dpp_add<0x142, 0xa>(v);  // row_bcast:15 -> rows 1,3
        v = dpp_add<0x143, 0xc>(v);  // row_bcast:31 -> rows 2,3
        part[j] = v;
    }

    __shared__ float sred[4][NCLS];
    const int wave = tid >> 6;
    const int lane = tid & 63;
    if (lane == 63) {
#pragma unroll
        for (int j = 0; j < NCLS; ++j) sred[wave][j] = part[j];
    }
    __syncthreads();

    if (tid == 0) {
        float logit[NCLS];
        float m = -1e30f;
#pragma unroll
        for (int j = 0; j < NCLS; ++j) {
            logit[j] = sred[0][j] + sred[1][j] + sred[2][j] + sred[3][j] + bias[j];
            m = fmaxf(m, logit[j]);
        }
        float s = 0.f;
#pragma unroll
        for (int j = 0; j < NCLS; ++j) s += __expf(logit[j] - m);
        const float lse = m + __logf(s);
        // 40 B/sample is 8-byte aligned for every b -> float2 stores.
        float2* o2 = reinterpret_cast<float2*>(out + b * NCLS);
#pragma unroll
        for (int j = 0; j < NCLS / 2; ++j)
            o2[j] = make_float2(logit[2 * j] - lse, logit[2 * j + 1] - lse);
    }
}

extern "C" void kernel_launch(void* const* d_in, const int* in_sizes, int n_in,
                              void* d_out, int out_size, void* d_ws, size_t ws_size,
                              hipStream_t stream) {
    const float* x    = (const float*)d_in[0];
    const float* qp   = (const float*)d_in[1];
    const float* W    = (const float*)d_in[2];
    const float* bias = (const float*)d_in[3];
    float* out = (float*)d_out;

    const int B = in_sizes[0] / NPIX;  // 2048
    quanv_fused<<<B, 256, 0, stream>>>(x, qp, W, bias, out);
}

// Round 3
// 10.248 us; speedup vs baseline: 1.2198x; 1.0037x over previous
//
#include <hip/hip_runtime.h>

// QuanvolutionHybrid — closed-form quantum circuit + fused matvec + log_softmax.
//
// Math: the 4-qubit circuit per patch reduces to per-wire Z expectations
//   z0 = cos(p0 + q0), z1 = cos(p1)*cos(q1), z2 = cos(p2 + q2), z3 = cos(p3)*cos(q3)
// and, after the CNOT chain (basis permutation; final bits are XORs of
// independent initial bits), measured features
//   f0 = z1*z2*z3, f1 = z0*z1, f2 = z0*z1*z2, f3 = z0*z1*z2*z3.
// Then logits = features @ W^T + b, out = log_softmax(logits).
//
// R2 change: ONE WAVE PER SAMPLE. Lane l owns patches {l, l+64, l+128} and
// lanes 0-3 additionally patch 192+l. Eliminates LDS, __syncthreads, the
// 4x-redundant DPP reduction, and the cross-wave serial tail. 4 samples per
// 256-thread block; every wave fully independent.

constexpr int NPIX = 784;   // 28*28
constexpr int NP   = 196;   // 14*14 patches
constexpr int NCLS = 10;

template <int Ctrl, int RowMask>
__device__ __forceinline__ float dpp_add(float x) {
    // x + dpp_shifted(x); masked/invalid dest lanes get old = 0.
    int s = __builtin_amdgcn_update_dpp(0, __float_as_int(x), Ctrl, RowMask, 0xf, false);
    return x + __int_as_float(s);
}

__global__ __launch_bounds__(256)
void quanv_wave(const float* __restrict__ x,     // [B,784]
                const float* __restrict__ qp,    // [4]
                const float* __restrict__ W,     // [10,784]
                const float* __restrict__ bias,  // [10]
                float* __restrict__ out,         // [B,10]
                int B)
{
    const int tid  = threadIdx.x;
    const int wave = tid >> 6;
    const int lane = tid & 63;
    const int b    = blockIdx.x * 4 + wave;
    if (b >= B) return;  // wave-uniform

    const float t0 = qp[0];
    const float c1 = __cosf(qp[1]);
    const float t2 = qp[2];
    const float c3 = __cosf(qp[3]);

    const float* __restrict__ xb = x + b * NPIX;

    float part[NCLS];
#pragma unroll
    for (int j = 0; j < NCLS; ++j) part[j] = 0.f;

#pragma unroll
    for (int i = 0; i < 4; ++i) {
        const int p = lane + 64 * i;          // patch id
        if (i < 3 || lane < NP - 192) {       // lanes 0-3 take a 4th patch
            const unsigned pu = (unsigned)p;
            const int pr = (int)((pu * 4682u) >> 16);   // p / 14 (valid 0..195)
            const int pc = p - pr * 14;
            const float* xr = xb + pr * 56 + pc * 2;
            const float2 top = *reinterpret_cast<const float2*>(xr);       // r,c / r,c+1
            const float2 bot = *reinterpret_cast<const float2*>(xr + 28);  // r+1,c / r+1,c+1

            const float z0 = __cosf(top.x + t0);
            const float z1 = __cosf(top.y) * c1;
            const float z2 = __cosf(bot.x + t2);
            const float z3 = __cosf(bot.y) * c3;

            const float f1 = z0 * z1;
            const float f2 = f1 * z2;
            const float f3 = f2 * z3;
            const float f0 = z1 * z2 * z3;

            const float4* Wp = reinterpret_cast<const float4*>(W) + p;  // row stride 196 float4
#pragma unroll
            for (int j = 0; j < NCLS; ++j) {
                const float4 w = Wp[j * (NPIX / 4)];
                part[j] += fmaf(f0, w.x, fmaf(f1, w.y, fmaf(f2, w.z, f3 * w.w)));
            }
        }
    }

    // DPP wave(64) reduction, pure VALU; totals land in lane 63.
#pragma unroll
    for (int j = 0; j < NCLS; ++j) {
        float v = part[j];
        v = dpp_add<0x111, 0xf>(v);  // row_shr:1
        v = dpp_add<0x112, 0xf>(v);  // row_shr:2
        v = dpp_add<0x114, 0xf>(v);  // row_shr:4
        v = dpp_add<0x118, 0xf>(v);  // row_shr:8
        v = dpp_add<0x142, 0xa>(v);  // row_bcast:15 -> rows 1,3
        v = dpp_add<0x143, 0xc>(v);  // row_bcast:31 -> rows 2,3
        part[j] = v;
    }

    if (lane == 63) {
        float logit[NCLS];
        float m = -1e30f;
#pragma unroll
        for (int j = 0; j < NCLS; ++j) {
            logit[j] = part[j] + bias[j];
            m = fmaxf(m, logit[j]);
        }
        float s = 0.f;
#pragma unroll
        for (int j = 0; j < NCLS; ++j) s += __expf(logit[j] - m);
        const float lse = m + __logf(s);
        float2* o2 = reinterpret_cast<float2*>(out + b * NCLS);  // 40B/sample -> 8B aligned
#pragma unroll
        for (int j = 0; j < NCLS / 2; ++j)
            o2[j] = make_float2(logit[2 * j] - lse, logit[2 * j + 1] - lse);
    }
}

extern "C" void kernel_launch(void* const* d_in, const int* in_sizes, int n_in,
                              void* d_out, int out_size, void* d_ws, size_t ws_size,
                              hipStream_t stream) {
    const float* x    = (const float*)d_in[0];
    const float* qp   = (const float*)d_in[1];
    const float* W    = (const float*)d_in[2];
    const float* bias = (const float*)d_in[3];
    float* out = (float*)d_out;

    const int B = in_sizes[0] / NPIX;  // 2048
    const int grid = (B + 3) / 4;      // 4 samples (waves) per block
    quanv_wave<<<grid, 256, 0, stream>>>(x, qp, W, bias, out, B);
}